// Round 8
// baseline (274.392 us; speedup 1.0000x reference)
//
#include <hip/hip_runtime.h>

#define HIDDEN 128
#define NRAD 6
#define NEMB 95
#define PLD 132   // P row stride in ushorts (264 B): rows spread 2*xi banks, 8B-aligned
#define STG 132   // stage row stride in floats

typedef short bf16x8 __attribute__((ext_vector_type(8)));
typedef float f32x4 __attribute__((ext_vector_type(4)));

__device__ __forceinline__ float fast_rcp(float x) {
    return __builtin_amdgcn_rcpf(x);
}
__device__ __forceinline__ float swishf(float v) {
    return v * fast_rcp(1.0f + __expf(-v));
}
// float -> bf16 (round-to-nearest-even)
__device__ __forceinline__ short f2bf(float f) {
    union { float f; unsigned u; } c; c.f = f;
    unsigned r = (c.u + 0x7FFFu + ((c.u >> 16) & 1u)) >> 16;
    return (short)(unsigned short)r;
}
__device__ __forceinline__ float bf2f(unsigned short u) {
    union { unsigned u; float f; } c; c.u = ((unsigned)u) << 16; return c.f;
}

// Barrier that waits only on LDS ops (lgkmcnt), NOT vmcnt — lets global
// stores from iteration t stay in flight across the barrier (§5 template).
__device__ __forceinline__ void barrier_lgkm() {
    asm volatile("s_waitcnt lgkmcnt(0)" ::: "memory");
    __builtin_amdgcn_s_barrier();
}

// P1[a][h] = bf16( b_lin[h] + sum_k emb[a][k]*w_lin[h][k]      )  k in [0,128)
// P2[a][h] = bf16(            sum_k emb[a][k]*w_lin[h][128+k]  )
__global__ void precompute_kernel(const float* __restrict__ emb,
                                  const float* __restrict__ w_lin,
                                  const float* __restrict__ b_lin,
                                  unsigned short* __restrict__ P1,
                                  unsigned short* __restrict__ P2) {
    __shared__ __align__(16) float erow[HIDDEN];
    const int a = blockIdx.x;
    const int h = threadIdx.x;
    erow[h] = emb[a * HIDDEN + h];
    __syncthreads();
    float acc1 = b_lin[h];
    float acc2 = 0.f;
    const float* __restrict__ w1 = w_lin + h * 384;
    const float* __restrict__ w2 = w1 + HIDDEN;
#pragma unroll 8
    for (int k = 0; k < HIDDEN; ++k) {
        acc1 += erow[k] * w1[k];
        acc2 += erow[k] * w2[k];
    }
    P1[a * PLD + h] = (unsigned short)f2bf(acc1);
    P2[a * PLD + h] = (unsigned short)f2bf(acc2);
}

struct MD {
    float2 ra, rb, rc;   // rbf[e][0..5]
    int xi, xj;          // xv[iv[e]], xv[jv[e]]
};

__device__ __forceinline__ MD load_md(int tile, int l15, int n_edges,
                                      const int* __restrict__ iv,
                                      const int* __restrict__ jv,
                                      const int* __restrict__ xv,
                                      const float* __restrict__ rbf) {
    int e = tile * 16 + l15;
    int ecl = (e < n_edges) ? e : (n_edges - 1);
    MD m;
    const float2* rp = reinterpret_cast<const float2*>(rbf + (size_t)ecl * NRAD);
    m.ra = rp[0];
    m.rb = rp[1];
    m.rc = rp[2];
    m.xi = xv[iv[ecl]];
    m.xj = xv[jv[ecl]];
    return m;
}

// Block-cooperative: per iteration the 4-wave block processes ONE 16-edge tile.
// Wave w owns channel tiles nt = 2w, 2w+1 (W3 fragments in REGISTERS, 32 VGPR).
// P1/P2 live in LDS as bf16 (no L2 gather traffic).  mfma_f32_16x16x32_bf16,
// transposed output: C[ch][e], lane = edge (lane&15).  Epilogue bounces e1/e2
// tiles through shared LDS -> block-flat 4KB-burst stores.  In-loop barriers
// wait lgkmcnt only, so stores pipeline across iterations.
__global__ __launch_bounds__(256, 2)
void edge_mfma_kernel(const int* __restrict__ xv,
                      const float* __restrict__ rbf,
                      const int* __restrict__ iv,
                      const int* __restrict__ jv,
                      const float* __restrict__ w_rbf0,
                      const float* __restrict__ b_rbf0,
                      const float* __restrict__ w_rbf1,
                      const float* __restrict__ w_lin,
                      const unsigned short* __restrict__ P1g,
                      const unsigned short* __restrict__ P2g,
                      float* __restrict__ out_e1,
                      float* __restrict__ out_e2,
                      int n_edges, int tiles_per_block, int n_tiles, int n_rows) {
    __shared__ __align__(16) unsigned short p1s[NEMB * PLD];
    __shared__ __align__(16) unsigned short p2s[NEMB * PLD];
    __shared__ __align__(16) float stg0[16 * STG];   // e1 stage
    __shared__ __align__(16) float stg1[16 * STG];   // e2 stage
    __shared__ float w0s[HIDDEN * 9];
    __shared__ float b0s[HIDDEN];

    const int tid = threadIdx.x;

    // ---- stage P tables into LDS (bf16) ----
    {
        const unsigned* __restrict__ g1 = reinterpret_cast<const unsigned*>(P1g);
        const unsigned* __restrict__ g2 = reinterpret_cast<const unsigned*>(P2g);
        unsigned* s1 = reinterpret_cast<unsigned*>(p1s);
        unsigned* s2 = reinterpret_cast<unsigned*>(p2s);
        const int n = (n_rows < NEMB ? n_rows : NEMB) * PLD / 2;
        for (int s = tid; s < n; s += 256) { s1[s] = g1[s]; s2[s] = g2[s]; }
    }
    if (tid < HIDDEN) {
#pragma unroll
        for (int r = 0; r < NRAD; ++r)
            w0s[tid * 9 + r] = w_rbf0[tid * NRAD + r];
        b0s[tid] = b_rbf0[tid];
    }

    const int wid = tid >> 6;
    const int lane = tid & 63;
    const int l15 = lane & 15;
    const int lg = lane >> 4;

    // ---- W3 + w1 fragments in registers (wave w -> nt = 2w, 2w+1) ----
    bf16x8 w3f[2][4];
    bf16x8 w1f[2];
#pragma unroll
    for (int n2 = 0; n2 < 2; ++n2) {
        const int h = (wid * 2 + n2) * 16 + l15;
        const float* wp = w_lin + h * 384 + 256;
#pragma unroll
        for (int ks = 0; ks < 4; ++ks) {
            const float4* s4 = reinterpret_cast<const float4*>(wp + (ks * 4 + lg) * 8);
            const float4 va = s4[0];
            const float4 vb = s4[1];
            bf16x8 fr;
            fr[0] = f2bf(va.x); fr[1] = f2bf(va.y);
            fr[2] = f2bf(va.z); fr[3] = f2bf(va.w);
            fr[4] = f2bf(vb.x); fr[5] = f2bf(vb.y);
            fr[6] = f2bf(vb.z); fr[7] = f2bf(vb.w);
            w3f[n2][ks] = fr;
        }
        bf16x8 f1;
#pragma unroll
        for (int r = 0; r < NRAD; ++r) f1[r] = f2bf(w_rbf1[h * NRAD + r]);
        f1[6] = 0; f1[7] = 0;
        w1f[n2] = f1;
    }
    __syncthreads();

    const int bt = blockIdx.x * tiles_per_block;
    const int btEnd = min(bt + tiles_per_block, n_tiles);
    if (bt >= btEnd) return;   // uniform per block

    const f32x4 zero4 = (f32x4){0.f, 0.f, 0.f, 0.f};
    MD cur = load_md(bt, l15, n_edges, iv, jv, xv, rbf);

    for (int t = bt; t < btEnd; ++t) {
        MD nxt = load_md(t + 1, l15, n_edges, iv, jv, xv, rbf);  // prefetch

        // ---- qd = rbf @ w1^T via MFMA (B nonzero only k<6, lg==0) ----
        bf16x8 rpad = (bf16x8){0, 0, 0, 0, 0, 0, 0, 0};
        if (lg == 0) {
            rpad[0] = f2bf(cur.ra.x); rpad[1] = f2bf(cur.ra.y);
            rpad[2] = f2bf(cur.rb.x); rpad[3] = f2bf(cur.rb.y);
            rpad[4] = f2bf(cur.rc.x); rpad[5] = f2bf(cur.rc.y);
        }
        f32x4 acc2[2];
#pragma unroll
        for (int n2 = 0; n2 < 2; ++n2)
            acc2[n2] = __builtin_amdgcn_mfma_f32_16x16x32_bf16(w1f[n2], rpad, zero4, 0, 0, 0);

        f32x4 acc[2] = {zero4, zero4};
#pragma unroll
        for (int ks = 0; ks < 4; ++ks) {
            // B fragment: rbf0^T[k][e=l15], k = ks*32 + lg*8 + j (lane-local)
            bf16x8 rb0;
#pragma unroll
            for (int j = 0; j < 8; ++j) {
                const int k = ks * 32 + lg * 8 + j;
                float tv = b0s[k]
                         + cur.ra.x * w0s[k * 9 + 0] + cur.ra.y * w0s[k * 9 + 1]
                         + cur.rb.x * w0s[k * 9 + 2] + cur.rb.y * w0s[k * 9 + 3]
                         + cur.rc.x * w0s[k * 9 + 4] + cur.rc.y * w0s[k * 9 + 5];
                rb0[j] = f2bf(swishf(tv));
            }
#pragma unroll
            for (int n2 = 0; n2 < 2; ++n2)
                acc[n2] = __builtin_amdgcn_mfma_f32_16x16x32_bf16(w3f[n2][ks], rb0, acc[n2], 0, 0, 0);
        }

        // ---- epilogue: P adds from LDS, swish, stage writes ----
#pragma unroll
        for (int n2 = 0; n2 < 2; ++n2) {
            const int ch0 = (wid * 2 + n2) * 16 + lg * 4;
            const uint2 u1 = *reinterpret_cast<const uint2*>(&p1s[cur.xi * PLD + ch0]);
            const uint2 u2 = *reinterpret_cast<const uint2*>(&p2s[cur.xj * PLD + ch0]);
            float pv[4];
            pv[0] = bf2f((unsigned short)(u1.x & 0xffff)) + bf2f((unsigned short)(u2.x & 0xffff));
            pv[1] = bf2f((unsigned short)(u1.x >> 16))    + bf2f((unsigned short)(u2.x >> 16));
            pv[2] = bf2f((unsigned short)(u1.y & 0xffff)) + bf2f((unsigned short)(u2.y & 0xffff));
            pv[3] = bf2f((unsigned short)(u1.y >> 16))    + bf2f((unsigned short)(u2.y >> 16));
            f32x4 v1;
#pragma unroll
            for (int q = 0; q < 4; ++q) {
                const float s = acc[n2][q] + pv[q];
                const float e1v = swishf(s);
                v1[q] = e1v;
                acc2[n2][q] *= e1v;
            }
            *reinterpret_cast<f32x4*>(&stg0[l15 * STG + ch0]) = v1;
            *reinterpret_cast<f32x4*>(&stg1[l15 * STG + ch0]) = acc2[n2];
        }
        barrier_lgkm();   // stage writes visible; stores from prev iters still in flight

        // ---- block-flat contiguous stores: 2 x 4KB bursts per array ----
        {
            const size_t base = (size_t)t * 16 * HIDDEN;
#pragma unroll
            for (int s = 0; s < 2; ++s) {
                const int idx = s * 1024 + tid * 4;
                const int e = idx >> 7;
                const f32x4 v1 = *reinterpret_cast<const f32x4*>(&stg0[e * STG + (idx & 127)]);
                const f32x4 v2 = *reinterpret_cast<const f32x4*>(&stg1[e * STG + (idx & 127)]);
                if (t * 16 + e < n_edges) {
                    *reinterpret_cast<f32x4*>(out_e1 + base + idx) = v1;
                    *reinterpret_cast<f32x4*>(out_e2 + base + idx) = v2;
                }
            }
        }
        barrier_lgkm();   // stage ds_reads done in all waves -> safe to overwrite
        cur = nxt;
    }
}

extern "C" void kernel_launch(void* const* d_in, const int* in_sizes, int n_in,
                              void* d_out, int out_size, void* d_ws, size_t ws_size,
                              hipStream_t stream) {
    const int*   xv     = (const int*)  d_in[0];
    const float* rbf    = (const float*)d_in[1];
    const int*   iv     = (const int*)  d_in[2];
    const int*   jv     = (const int*)  d_in[3];
    const float* emb    = (const float*)d_in[4];
    const float* w_rbf0 = (const float*)d_in[5];
    const float* b_rbf0 = (const float*)d_in[6];
    const float* w_lin  = (const float*)d_in[7];
    const float* b_lin  = (const float*)d_in[8];
    const float* w_rbf1 = (const float*)d_in[9];

    const int n_edges = in_sizes[2];
    const int n_emb_rows = in_sizes[4] / HIDDEN;   // 95

    unsigned short* P1 = (unsigned short*)d_ws;
    unsigned short* P2 = P1 + (size_t)NEMB * PLD;

    float* out_e1 = (float*)d_out;
    float* out_e2 = out_e1 + (size_t)n_edges * HIDDEN;

    precompute_kernel<<<n_emb_rows, HIDDEN, 0, stream>>>(emb, w_lin, b_lin, P1, P2);

    const int n_tiles = (n_edges + 15) / 16;
    const int grid = 512;                          // 2 blocks/CU (LDS-limited)
    const int tpb = (n_tiles + grid - 1) / grid;
    edge_mfma_kernel<<<grid, 256, 0, stream>>>(xv, rbf, iv, jv,
                                               w_rbf0, b_rbf0, w_rbf1, w_lin,
                                               P1, P2, out_e1, out_e2,
                                               n_edges, tpb, n_tiles, n_emb_rows);
}

// Round 9
// 184.028 us; speedup vs baseline: 1.4910x; 1.4910x over previous
//
#include <hip/hip_runtime.h>

#define HIDDEN 128
#define NRAD 6
#define NEMB 95
#define PLD 132   // P row stride in ushorts (264 B)
#define STG 132   // stage row stride in floats

typedef short bf16x8 __attribute__((ext_vector_type(8)));
typedef float f32x4 __attribute__((ext_vector_type(4)));

__device__ __forceinline__ float fast_rcp(float x) {
    return __builtin_amdgcn_rcpf(x);
}
__device__ __forceinline__ float swishf(float v) {
    return v * fast_rcp(1.0f + __expf(-v));
}
// float -> bf16 (round-to-nearest-even)
__device__ __forceinline__ short f2bf(float f) {
    union { float f; unsigned u; } c; c.f = f;
    unsigned r = (c.u + 0x7FFFu + ((c.u >> 16) & 1u)) >> 16;
    return (short)(unsigned short)r;
}
__device__ __forceinline__ float bf2f(unsigned short u) {
    union { unsigned u; float f; } c; c.u = ((unsigned)u) << 16; return c.f;
}

// Barrier that waits only on LDS ops (lgkmcnt), NOT vmcnt.
__device__ __forceinline__ void barrier_lgkm() {
    asm volatile("s_waitcnt lgkmcnt(0)" ::: "memory");
    __builtin_amdgcn_s_barrier();
}

// P1[a][h] = bf16( b_lin[h] + sum_k emb[a][k]*w_lin[h][k]      )  k in [0,128)
// P2[a][h] = bf16(            sum_k emb[a][k]*w_lin[h][128+k]  )
__global__ void precompute_kernel(const float* __restrict__ emb,
                                  const float* __restrict__ w_lin,
                                  const float* __restrict__ b_lin,
                                  unsigned short* __restrict__ P1,
                                  unsigned short* __restrict__ P2) {
    __shared__ __align__(16) float erow[HIDDEN];
    const int a = blockIdx.x;
    const int h = threadIdx.x;
    erow[h] = emb[a * HIDDEN + h];
    __syncthreads();
    float acc1 = b_lin[h];
    float acc2 = 0.f;
    const float* __restrict__ w1 = w_lin + h * 384;
    const float* __restrict__ w2 = w1 + HIDDEN;
#pragma unroll 8
    for (int k = 0; k < HIDDEN; ++k) {
        acc1 += erow[k] * w1[k];
        acc2 += erow[k] * w2[k];
    }
    P1[a * PLD + h] = (unsigned short)f2bf(acc1);
    P2[a * PLD + h] = (unsigned short)f2bf(acc2);
}

struct MD {
    float2 ra, rb, rc;   // rbf[e][0..5]
    int xi, xj;          // xv[iv[e]], xv[jv[e]]
};

__device__ __forceinline__ MD load_md(int tile, int l15, int n_edges,
                                      const int* __restrict__ iv,
                                      const int* __restrict__ jv,
                                      const int* __restrict__ xv,
                                      const float* __restrict__ rbf) {
    int e = tile * 16 + l15;
    int ecl = (e < n_edges) ? e : (n_edges - 1);
    MD m;
    const float2* rp = reinterpret_cast<const float2*>(rbf + (size_t)ecl * NRAD);
    m.ra = rp[0];
    m.rb = rp[1];
    m.rc = rp[2];
    m.xi = xv[iv[ecl]];
    m.xj = xv[jv[ecl]];
    return m;
}

// Block-cooperative, one 16-edge tile per iteration.  Wave w owns channel
// tiles nt=2w,2w+1 (W3 in regs) AND computes the rbf0 B-fragment slab ks=w
// from REGISTER-resident w0/b0 (k-set per lane is fixed: w*32+lg*8+j) —
// zero LDS reads in the A-build.  Fragments exchanged via a 4 KB LDS stage.
// P1/P2 in LDS (bf16).  Epilogue bounces e1/e2 through LDS -> 4 KB bursts.
__global__ __launch_bounds__(256, 2)
void edge_mfma_kernel(const int* __restrict__ xv,
                      const float* __restrict__ rbf,
                      const int* __restrict__ iv,
                      const int* __restrict__ jv,
                      const float* __restrict__ w_rbf0,
                      const float* __restrict__ b_rbf0,
                      const float* __restrict__ w_rbf1,
                      const float* __restrict__ w_lin,
                      const unsigned short* __restrict__ P1g,
                      const unsigned short* __restrict__ P2g,
                      float* __restrict__ out_e1,
                      float* __restrict__ out_e2,
                      int n_edges, int tiles_per_block, int n_tiles, int n_rows) {
    __shared__ __align__(16) unsigned short p1s[NEMB * PLD];
    __shared__ __align__(16) unsigned short p2s[NEMB * PLD];
    __shared__ __align__(16) float stg0[16 * STG];     // e1 stage
    __shared__ __align__(16) float stg1[16 * STG];     // e2 stage
    __shared__ __align__(16) short fragS[4 * 4 * 16 * 8];  // [ks][lg][e] bf16x8

    const int tid = threadIdx.x;

    // ---- stage P tables into LDS (bf16) ----
    {
        const unsigned* __restrict__ g1 = reinterpret_cast<const unsigned*>(P1g);
        const unsigned* __restrict__ g2 = reinterpret_cast<const unsigned*>(P2g);
        unsigned* s1 = reinterpret_cast<unsigned*>(p1s);
        unsigned* s2 = reinterpret_cast<unsigned*>(p2s);
        const int n = (n_rows < NEMB ? n_rows : NEMB) * PLD / 2;
        for (int s = tid; s < n; s += 256) { s1[s] = g1[s]; s2[s] = g2[s]; }
    }

    const int wid = tid >> 6;
    const int lane = tid & 63;
    const int l15 = lane & 15;
    const int lg = lane >> 4;

    // ---- register-resident w0/b0 for this lane's FIXED k-set ----
    const int kbase = wid * 32 + lg * 8;
    float w0r[8][6], b0r[8];
#pragma unroll
    for (int j = 0; j < 8; ++j) {
        const float2* wp = reinterpret_cast<const float2*>(w_rbf0 + (kbase + j) * NRAD);
        const float2 a = wp[0], b = wp[1], c = wp[2];
        w0r[j][0] = a.x; w0r[j][1] = a.y;
        w0r[j][2] = b.x; w0r[j][3] = b.y;
        w0r[j][4] = c.x; w0r[j][5] = c.y;
        b0r[j] = b_rbf0[kbase + j];
    }

    // ---- W3 + w1 fragments in registers (wave w -> nt = 2w, 2w+1) ----
    bf16x8 w3f[2][4];
    bf16x8 w1f[2];
#pragma unroll
    for (int n2 = 0; n2 < 2; ++n2) {
        const int h = (wid * 2 + n2) * 16 + l15;
        const float* wp = w_lin + h * 384 + 256;
#pragma unroll
        for (int ks = 0; ks < 4; ++ks) {
            const float4* s4 = reinterpret_cast<const float4*>(wp + (ks * 4 + lg) * 8);
            const float4 va = s4[0];
            const float4 vb = s4[1];
            bf16x8 fr;
            fr[0] = f2bf(va.x); fr[1] = f2bf(va.y);
            fr[2] = f2bf(va.z); fr[3] = f2bf(va.w);
            fr[4] = f2bf(vb.x); fr[5] = f2bf(vb.y);
            fr[6] = f2bf(vb.z); fr[7] = f2bf(vb.w);
            w3f[n2][ks] = fr;
        }
        bf16x8 f1;
#pragma unroll
        for (int r = 0; r < NRAD; ++r) f1[r] = f2bf(w_rbf1[h * NRAD + r]);
        f1[6] = 0; f1[7] = 0;
        w1f[n2] = f1;
    }
    __syncthreads();   // p-tables staged

    const int bt = blockIdx.x * tiles_per_block;
    const int btEnd = min(bt + tiles_per_block, n_tiles);
    if (bt >= btEnd) return;   // uniform per block

    const f32x4 zero4 = (f32x4){0.f, 0.f, 0.f, 0.f};
    MD cur = load_md(bt, l15, n_edges, iv, jv, xv, rbf);

    for (int t = bt; t < btEnd; ++t) {
        MD nxt = load_md(t + 1, l15, n_edges, iv, jv, xv, rbf);  // prefetch

        // ---- A-build (register-only): slab ks = wid, k = kbase + j ----
        bf16x8 myfrag;
#pragma unroll
        for (int j = 0; j < 8; ++j) {
            float tv = b0r[j]
                     + cur.ra.x * w0r[j][0] + cur.ra.y * w0r[j][1]
                     + cur.rb.x * w0r[j][2] + cur.rb.y * w0r[j][3]
                     + cur.rc.x * w0r[j][4] + cur.rc.y * w0r[j][5];
            myfrag[j] = f2bf(swishf(tv));
        }
        *reinterpret_cast<bf16x8*>(&fragS[((wid * 4 + lg) * 16 + l15) * 8]) = myfrag;

        // ---- qd = rbf @ w1^T via MFMA (register-only while frag lands) ----
        bf16x8 rpad = (bf16x8){0, 0, 0, 0, 0, 0, 0, 0};
        if (lg == 0) {
            rpad[0] = f2bf(cur.ra.x); rpad[1] = f2bf(cur.ra.y);
            rpad[2] = f2bf(cur.rb.x); rpad[3] = f2bf(cur.rb.y);
            rpad[4] = f2bf(cur.rc.x); rpad[5] = f2bf(cur.rc.y);
        }
        f32x4 acc2[2];
#pragma unroll
        for (int n2 = 0; n2 < 2; ++n2)
            acc2[n2] = __builtin_amdgcn_mfma_f32_16x16x32_bf16(w1f[n2], rpad, zero4, 0, 0, 0);

        barrier_lgkm();   // fragment exchange visible

        bf16x8 bfrag[4];
#pragma unroll
        for (int ks = 0; ks < 4; ++ks)
            bfrag[ks] = *reinterpret_cast<const bf16x8*>(
                &fragS[((ks * 4 + lg) * 16 + l15) * 8]);

        f32x4 acc[2] = {zero4, zero4};
#pragma unroll
        for (int ks = 0; ks < 4; ++ks)
#pragma unroll
            for (int n2 = 0; n2 < 2; ++n2)
                acc[n2] = __builtin_amdgcn_mfma_f32_16x16x32_bf16(w3f[n2][ks], bfrag[ks], acc[n2], 0, 0, 0);

        // ---- epilogue: P adds from LDS, swish, stage writes ----
#pragma unroll
        for (int n2 = 0; n2 < 2; ++n2) {
            const int ch0 = (wid * 2 + n2) * 16 + lg * 4;
            const uint2 u1 = *reinterpret_cast<const uint2*>(&p1s[cur.xi * PLD + ch0]);
            const uint2 u2 = *reinterpret_cast<const uint2*>(&p2s[cur.xj * PLD + ch0]);
            float pv[4];
            pv[0] = bf2f((unsigned short)(u1.x & 0xffff)) + bf2f((unsigned short)(u2.x & 0xffff));
            pv[1] = bf2f((unsigned short)(u1.x >> 16))    + bf2f((unsigned short)(u2.x >> 16));
            pv[2] = bf2f((unsigned short)(u1.y & 0xffff)) + bf2f((unsigned short)(u2.y & 0xffff));
            pv[3] = bf2f((unsigned short)(u1.y >> 16))    + bf2f((unsigned short)(u2.y >> 16));
            f32x4 v1;
#pragma unroll
            for (int q = 0; q < 4; ++q) {
                const float s = acc[n2][q] + pv[q];
                const float e1v = swishf(s);
                v1[q] = e1v;
                acc2[n2][q] *= e1v;
            }
            *reinterpret_cast<f32x4*>(&stg0[l15 * STG + ch0]) = v1;
            *reinterpret_cast<f32x4*>(&stg1[l15 * STG + ch0]) = acc2[n2];
        }
        barrier_lgkm();   // stage writes visible; frag reads also drained

        // ---- block-flat contiguous stores: 2 x 4KB bursts per array ----
        {
            const size_t base = (size_t)t * 16 * HIDDEN;
#pragma unroll
            for (int s = 0; s < 2; ++s) {
                const int idx = s * 1024 + tid * 4;
                const int e = idx >> 7;
                const f32x4 v1 = *reinterpret_cast<const f32x4*>(&stg0[e * STG + (idx & 127)]);
                const f32x4 v2 = *reinterpret_cast<const f32x4*>(&stg1[e * STG + (idx & 127)]);
                if (t * 16 + e < n_edges) {
                    *reinterpret_cast<f32x4*>(out_e1 + base + idx) = v1;
                    *reinterpret_cast<f32x4*>(out_e2 + base + idx) = v2;
                }
            }
        }
        barrier_lgkm();   // stage reads done -> safe to overwrite next iter
        cur = nxt;
    }
}

extern "C" void kernel_launch(void* const* d_in, const int* in_sizes, int n_in,
                              void* d_out, int out_size, void* d_ws, size_t ws_size,
                              hipStream_t stream) {
    const int*   xv     = (const int*)  d_in[0];
    const float* rbf    = (const float*)d_in[1];
    const int*   iv     = (const int*)  d_in[2];
    const int*   jv     = (const int*)  d_in[3];
    const float* emb    = (const float*)d_in[4];
    const float* w_rbf0 = (const float*)d_in[5];
    const float* b_rbf0 = (const float*)d_in[6];
    const float* w_lin  = (const float*)d_in[7];
    const float* b_lin  = (const float*)d_in[8];
    const float* w_rbf1 = (const float*)d_in[9];

    const int n_edges = in_sizes[2];
    const int n_emb_rows = in_sizes[4] / HIDDEN;   // 95

    unsigned short* P1 = (unsigned short*)d_ws;
    unsigned short* P2 = P1 + (size_t)NEMB * PLD;

    float* out_e1 = (float*)d_out;
    float* out_e2 = out_e1 + (size_t)n_edges * HIDDEN;

    precompute_kernel<<<n_emb_rows, HIDDEN, 0, stream>>>(emb, w_lin, b_lin, P1, P2);

    const int n_tiles = (n_edges + 15) / 16;
    const int grid = 512;                          // 2 blocks/CU (LDS-limited)
    const int tpb = (n_tiles + grid - 1) / grid;
    edge_mfma_kernel<<<grid, 256, 0, stream>>>(xv, rbf, iv, jv,
                                               w_rbf0, b_rbf0, w_rbf1, w_lin,
                                               P1, P2, out_e1, out_e2,
                                               n_edges, tpb, n_tiles, n_emb_rows);
}

// Round 10
// 173.607 us; speedup vs baseline: 1.5805x; 1.0600x over previous
//
#include <hip/hip_runtime.h>

#define HIDDEN 128
#define NRAD 6
#define NEMB 95
#define PLD 132   // P row stride in ushorts (264 B): rows rotate banks
#define SLD 136   // bf16 stage row stride in ushorts (272 B): 8B-aligned, banks rotate by 4

typedef short bf16x8 __attribute__((ext_vector_type(8)));
typedef float f32x4 __attribute__((ext_vector_type(4)));

__device__ __forceinline__ float fast_rcp(float x) {
    return __builtin_amdgcn_rcpf(x);
}
__device__ __forceinline__ float swishf(float v) {
    return v * fast_rcp(1.0f + __expf(-v));
}
// float -> bf16 (round-to-nearest-even) — used in precompute/weight init only
__device__ __forceinline__ short f2bf(float f) {
    union { float f; unsigned u; } c; c.f = f;
    unsigned r = (c.u + 0x7FFFu + ((c.u >> 16) & 1u)) >> 16;
    return (short)(unsigned short)r;
}
__device__ __forceinline__ float bf2f(unsigned short u) {
    union { unsigned u; float f; } c; c.u = ((unsigned)u) << 16; return c.f;
}
// pack two floats to packed-bf16 (TRUNCATED) in one v_perm_b32
__device__ __forceinline__ unsigned pk(float lo, float hi) {
    return __builtin_amdgcn_perm(__float_as_uint(hi), __float_as_uint(lo), 0x07060302u);
}
__device__ __forceinline__ float xlo(unsigned u) {
    union { unsigned u; float f; } c; c.u = u << 16; return c.f;
}
__device__ __forceinline__ float xhi(unsigned u) {
    union { unsigned u; float f; } c; c.u = u & 0xffff0000u; return c.f;
}

// Barrier that waits only on LDS ops (lgkmcnt), NOT vmcnt.
__device__ __forceinline__ void barrier_lgkm() {
    asm volatile("s_waitcnt lgkmcnt(0)" ::: "memory");
    __builtin_amdgcn_s_barrier();
}

// P1[a][h] = bf16( b_lin[h] + sum_k emb[a][k]*w_lin[h][k]      )  k in [0,128)
// P2[a][h] = bf16(            sum_k emb[a][k]*w_lin[h][128+k]  )
__global__ void precompute_kernel(const float* __restrict__ emb,
                                  const float* __restrict__ w_lin,
                                  const float* __restrict__ b_lin,
                                  unsigned short* __restrict__ P1,
                                  unsigned short* __restrict__ P2) {
    __shared__ __align__(16) float erow[HIDDEN];
    const int a = blockIdx.x;
    const int h = threadIdx.x;
    erow[h] = emb[a * HIDDEN + h];
    __syncthreads();
    float acc1 = b_lin[h];
    float acc2 = 0.f;
    const float* __restrict__ w1 = w_lin + h * 384;
    const float* __restrict__ w2 = w1 + HIDDEN;
#pragma unroll 8
    for (int k = 0; k < HIDDEN; ++k) {
        acc1 += erow[k] * w1[k];
        acc2 += erow[k] * w2[k];
    }
    P1[a * PLD + h] = (unsigned short)f2bf(acc1);
    P2[a * PLD + h] = (unsigned short)f2bf(acc2);
}

struct RawMD {
    float2 ra, rb, rc;   // rbf[e][0..5]
    int ii, jj;          // iv[e], jv[e]
};

__device__ __forceinline__ RawMD load_raw(int tile, int l15, int n_edges,
                                          const int* __restrict__ iv,
                                          const int* __restrict__ jv,
                                          const float* __restrict__ rbf) {
    int e = tile * 16 + l15;
    int ecl = (e < n_edges) ? e : (n_edges - 1);
    RawMD m;
    const float2* rp = reinterpret_cast<const float2*>(rbf + (size_t)ecl * NRAD);
    m.ra = rp[0];
    m.rb = rp[1];
    m.rc = rp[2];
    m.ii = iv[ecl];
    m.jj = jv[ecl];
    return m;
}

// Block-cooperative, one 16-edge tile per iteration, 2-deep pipeline:
//   raw MD loads 2 tiles ahead; xv gathers 1 tile ahead; global stores run
//   one tile BEHIND compute (bf16 double-buffered LDS stage) so no vmcnt
//   wait ever forces a recent store burst to drain.
// Wave w owns channel tiles nt=2w,2w+1 (W3 in regs) and builds the rbf0
// B-slab ks=w from register-resident w0/b0.  P1/P2 in LDS (bf16).
// 2 lgkm-barriers per iteration:
//   bar1: fragS(t) writes visible     (WAR on fragS guaranteed by bar2(t-1))
//   bar2: stage[t&1] writes visible   (WAR on stage: reads of [t&1] happened
//         in store-phase(t-1) before bar2(t-1))
__global__ __launch_bounds__(256, 2)
void edge_mfma_kernel(const int* __restrict__ xv,
                      const float* __restrict__ rbf,
                      const int* __restrict__ iv,
                      const int* __restrict__ jv,
                      const float* __restrict__ w_rbf0,
                      const float* __restrict__ b_rbf0,
                      const float* __restrict__ w_rbf1,
                      const float* __restrict__ w_lin,
                      const unsigned short* __restrict__ P1g,
                      const unsigned short* __restrict__ P2g,
                      float* __restrict__ out_e1,
                      float* __restrict__ out_e2,
                      int n_edges, int tiles_per_block, int n_tiles, int n_rows) {
    __shared__ __align__(16) unsigned short p1s[NEMB * PLD];
    __shared__ __align__(16) unsigned short p2s[NEMB * PLD];
    __shared__ __align__(16) unsigned short stgE1[2][16 * SLD];  // e1, bf16, dbuf
    __shared__ __align__(16) unsigned short stgE2[2][16 * SLD];  // e2, bf16, dbuf
    __shared__ __align__(16) short fragS[4 * 4 * 16 * 8];        // [ks][lg][e] bf16x8

    const int tid = threadIdx.x;

    // ---- stage P tables into LDS (bf16) ----
    {
        const unsigned* __restrict__ g1 = reinterpret_cast<const unsigned*>(P1g);
        const unsigned* __restrict__ g2 = reinterpret_cast<const unsigned*>(P2g);
        unsigned* s1 = reinterpret_cast<unsigned*>(p1s);
        unsigned* s2 = reinterpret_cast<unsigned*>(p2s);
        const int n = (n_rows < NEMB ? n_rows : NEMB) * PLD / 2;
        for (int s = tid; s < n; s += 256) { s1[s] = g1[s]; s2[s] = g2[s]; }
    }

    const int wid = tid >> 6;
    const int lane = tid & 63;
    const int l15 = lane & 15;
    const int lg = lane >> 4;

    // ---- register-resident w0/b0 for this lane's FIXED k-set ----
    const int kbase = wid * 32 + lg * 8;
    float w0r[8][6], b0r[8];
#pragma unroll
    for (int j = 0; j < 8; ++j) {
        const float2* wp = reinterpret_cast<const float2*>(w_rbf0 + (kbase + j) * NRAD);
        const float2 a = wp[0], b = wp[1], c = wp[2];
        w0r[j][0] = a.x; w0r[j][1] = a.y;
        w0r[j][2] = b.x; w0r[j][3] = b.y;
        w0r[j][4] = c.x; w0r[j][5] = c.y;
        b0r[j] = b_rbf0[kbase + j];
    }

    // ---- W3 + w1 fragments in registers (wave w -> nt = 2w, 2w+1) ----
    bf16x8 w3f[2][4];
    bf16x8 w1f[2];
#pragma unroll
    for (int n2 = 0; n2 < 2; ++n2) {
        const int h = (wid * 2 + n2) * 16 + l15;
        const float* wp = w_lin + h * 384 + 256;
#pragma unroll
        for (int ks = 0; ks < 4; ++ks) {
            const float4* s4 = reinterpret_cast<const float4*>(wp + (ks * 4 + lg) * 8);
            const float4 va = s4[0];
            const float4 vb = s4[1];
            bf16x8 fr;
            fr[0] = f2bf(va.x); fr[1] = f2bf(va.y);
            fr[2] = f2bf(va.z); fr[3] = f2bf(va.w);
            fr[4] = f2bf(vb.x); fr[5] = f2bf(vb.y);
            fr[6] = f2bf(vb.z); fr[7] = f2bf(vb.w);
            w3f[n2][ks] = fr;
        }
        bf16x8 f1;
#pragma unroll
        for (int r = 0; r < NRAD; ++r) f1[r] = f2bf(w_rbf1[h * NRAD + r]);
        f1[6] = 0; f1[7] = 0;
        w1f[n2] = f1;
    }
    __syncthreads();   // p-tables staged

    const int bt = blockIdx.x * tiles_per_block;
    const int btEnd = min(bt + tiles_per_block, n_tiles);
    if (bt >= btEnd) return;   // uniform per block

    const f32x4 zero4 = (f32x4){0.f, 0.f, 0.f, 0.f};

    // ---- pipeline prologue ----
    RawMD curR = load_raw(bt, l15, n_edges, iv, jv, rbf);
    RawMD nxtR = load_raw(bt + 1, l15, n_edges, iv, jv, rbf);
    int cxi = xv[curR.ii];
    int cxj = xv[curR.jj];

    for (int t = bt; t < btEnd; ++t) {
        // issue loads 2 ahead (raw) and 1 ahead (xv gathers)
        RawMD n2R = load_raw(t + 2, l15, n_edges, iv, jv, rbf);
        const int gxi = xv[nxtR.ii];
        const int gxj = xv[nxtR.jj];

        // ---- A-build (register-only): slab ks = wid, k = kbase + j ----
        float sv[8];
#pragma unroll
        for (int j = 0; j < 8; ++j) {
            float tv = b0r[j]
                     + curR.ra.x * w0r[j][0] + curR.ra.y * w0r[j][1]
                     + curR.rb.x * w0r[j][2] + curR.rb.y * w0r[j][3]
                     + curR.rc.x * w0r[j][4] + curR.rc.y * w0r[j][5];
            sv[j] = swishf(tv);
        }
        {
            uint4 mf;
            mf.x = pk(sv[0], sv[1]); mf.y = pk(sv[2], sv[3]);
            mf.z = pk(sv[4], sv[5]); mf.w = pk(sv[6], sv[7]);
            *reinterpret_cast<uint4*>(&fragS[((wid * 4 + lg) * 16 + l15) * 8]) = mf;
        }

        // ---- qd = rbf @ w1^T via MFMA (register-only while frag lands) ----
        union { uint4 u; bf16x8 b; } rp4;
        rp4.u = (uint4){0u, 0u, 0u, 0u};
        if (lg == 0) {
            rp4.u.x = pk(curR.ra.x, curR.ra.y);
            rp4.u.y = pk(curR.rb.x, curR.rb.y);
            rp4.u.z = pk(curR.rc.x, curR.rc.y);
        }
        f32x4 acc2[2];
#pragma unroll
        for (int n2 = 0; n2 < 2; ++n2)
            acc2[n2] = __builtin_amdgcn_mfma_f32_16x16x32_bf16(w1f[n2], rp4.b, zero4, 0, 0, 0);

        barrier_lgkm();   // bar1: fragment exchange visible

        bf16x8 bfrag[4];
#pragma unroll
        for (int ks = 0; ks < 4; ++ks)
            bfrag[ks] = *reinterpret_cast<const bf16x8*>(
                &fragS[((ks * 4 + lg) * 16 + l15) * 8]);

        f32x4 acc[2] = {zero4, zero4};
#pragma unroll
        for (int ks = 0; ks < 4; ++ks)
#pragma unroll
            for (int n2 = 0; n2 < 2; ++n2)
                acc[n2] = __builtin_amdgcn_mfma_f32_16x16x32_bf16(w3f[n2][ks], bfrag[ks], acc[n2], 0, 0, 0);

        // ---- STORE PHASE for tile t-1 (overlaps MFMA shadow) ----
        if (t != bt) {
            const int tp = t - 1;
            const int b = tp & 1;
            const size_t base = (size_t)tp * 16 * HIDDEN;
#pragma unroll
            for (int s = 0; s < 2; ++s) {
                const int idx = s * 1024 + tid * 4;
                const int e = idx >> 7;
                const int ch = idx & 127;
                const uint2 u1 = *reinterpret_cast<const uint2*>(&stgE1[b][e * SLD + ch]);
                const uint2 u2 = *reinterpret_cast<const uint2*>(&stgE2[b][e * SLD + ch]);
                if (tp * 16 + e < n_edges) {
                    f32x4 v1, v2;
                    v1[0] = xlo(u1.x); v1[1] = xhi(u1.x); v1[2] = xlo(u1.y); v1[3] = xhi(u1.y);
                    v2[0] = xlo(u2.x); v2[1] = xhi(u2.x); v2[2] = xlo(u2.y); v2[3] = xhi(u2.y);
                    *reinterpret_cast<f32x4*>(out_e1 + base + idx) = v1;
                    *reinterpret_cast<f32x4*>(out_e2 + base + idx) = v2;
                }
            }
        }

        // ---- epilogue: P adds from LDS, swish, bf16 stage writes ----
#pragma unroll
        for (int n2 = 0; n2 < 2; ++n2) {
            const int ch0 = (wid * 2 + n2) * 16 + lg * 4;
            const uint2 u1 = *reinterpret_cast<const uint2*>(&p1s[cxi * PLD + ch0]);
            const uint2 u2 = *reinterpret_cast<const uint2*>(&p2s[cxj * PLD + ch0]);
            float pv[4];
            pv[0] = bf2f((unsigned short)(u1.x & 0xffff)) + bf2f((unsigned short)(u2.x & 0xffff));
            pv[1] = bf2f((unsigned short)(u1.x >> 16))    + bf2f((unsigned short)(u2.x >> 16));
            pv[2] = bf2f((unsigned short)(u1.y & 0xffff)) + bf2f((unsigned short)(u2.y & 0xffff));
            pv[3] = bf2f((unsigned short)(u1.y >> 16))    + bf2f((unsigned short)(u2.y >> 16));
            float e1v[4], e2v[4];
#pragma unroll
            for (int q = 0; q < 4; ++q) {
                const float s = acc[n2][q] + pv[q];
                e1v[q] = swishf(s);
                e2v[q] = acc2[n2][q] * e1v[q];
            }
            const int so = l15 * SLD + ch0;
            *reinterpret_cast<uint2*>(&stgE1[t & 1][so]) =
                make_uint2(pk(e1v[0], e1v[1]), pk(e1v[2], e1v[3]));
            *reinterpret_cast<uint2*>(&stgE2[t & 1][so]) =
                make_uint2(pk(e2v[0], e2v[1]), pk(e2v[2], e2v[3]));
        }
        barrier_lgkm();   // bar2: stage writes visible; fragS reads drained

        curR = nxtR; nxtR = n2R; cxi = gxi; cxj = gxj;
    }

    // ---- drain: store phase for the last tile ----
    {
        const int tp = btEnd - 1;
        const int b = tp & 1;
        const size_t base = (size_t)tp * 16 * HIDDEN;
#pragma unroll
        for (int s = 0; s < 2; ++s) {
            const int idx = s * 1024 + tid * 4;
            const int e = idx >> 7;
            const int ch = idx & 127;
            const uint2 u1 = *reinterpret_cast<const uint2*>(&stgE1[b][e * SLD + ch]);
            const uint2 u2 = *reinterpret_cast<const uint2*>(&stgE2[b][e * SLD + ch]);
            if (tp * 16 + e < n_edges) {
                f32x4 v1, v2;
                v1[0] = xlo(u1.x); v1[1] = xhi(u1.x); v1[2] = xlo(u1.y); v1[3] = xhi(u1.y);
                v2[0] = xlo(u2.x); v2[1] = xhi(u2.x); v2[2] = xlo(u2.y); v2[3] = xhi(u2.y);
                *reinterpret_cast<f32x4*>(out_e1 + base + idx) = v1;
                *reinterpret_cast<f32x4*>(out_e2 + base + idx) = v2;
            }
        }
    }
}

extern "C" void kernel_launch(void* const* d_in, const int* in_sizes, int n_in,
                              void* d_out, int out_size, void* d_ws, size_t ws_size,
                              hipStream_t stream) {
    const int*   xv     = (const int*)  d_in[0];
    const float* rbf    = (const float*)d_in[1];
    const int*   iv     = (const int*)  d_in[2];
    const int*   jv     = (const int*)  d_in[3];
    const float* emb    = (const float*)d_in[4];
    const float* w_rbf0 = (const float*)d_in[5];
    const float* b_rbf0 = (const float*)d_in[6];
    const float* w_lin  = (const float*)d_in[7];
    const float* b_lin  = (const float*)d_in[8];
    const float* w_rbf1 = (const float*)d_in[9];

    const int n_edges = in_sizes[2];
    const int n_emb_rows = in_sizes[4] / HIDDEN;   // 95

    unsigned short* P1 = (unsigned short*)d_ws;
    unsigned short* P2 = P1 + (size_t)NEMB * PLD;

    float* out_e1 = (float*)d_out;
    float* out_e2 = out_e1 + (size_t)n_edges * HIDDEN;

    precompute_kernel<<<n_emb_rows, HIDDEN, 0, stream>>>(emb, w_lin, b_lin, P1, P2);

    const int n_tiles = (n_edges + 15) / 16;
    const int grid = 512;                          // 2 blocks/CU (LDS-limited)
    const int tpb = (n_tiles + grid - 1) / grid;
    edge_mfma_kernel<<<grid, 256, 0, stream>>>(xv, rbf, iv, jv,
                                               w_rbf0, b_rbf0, w_rbf1, w_lin,
                                               P1, P2, out_e1, out_e2,
                                               n_edges, tpb, n_tiles, n_emb_rows);
}

// Round 11
// 158.899 us; speedup vs baseline: 1.7268x; 1.0926x over previous
//
#include <hip/hip_runtime.h>

#define HIDDEN 128
#define NRAD 6
#define NEMB 95

typedef short bf16x8 __attribute__((ext_vector_type(8)));
typedef float f32x4 __attribute__((ext_vector_type(4)));

__device__ __forceinline__ float fast_rcp(float x) { return __builtin_amdgcn_rcpf(x); }
__device__ __forceinline__ float swishf(float v) { return v * fast_rcp(1.0f + __expf(-v)); }
// float -> bf16 (round-to-nearest-even)
__device__ __forceinline__ short f2bf(float f) {
    union { float f; unsigned u; } c; c.f = f;
    unsigned r = (c.u + 0x7FFFu + ((c.u >> 16) & 1u)) >> 16;
    return (short)(unsigned short)r;
}
__device__ __forceinline__ float bf2f(unsigned short u) {
    union { unsigned u; float f; } c; c.u = ((unsigned)u) << 16; return c.f;
}
// pack two floats to packed-bf16 (truncated) in one v_perm_b32
__device__ __forceinline__ unsigned pk(float lo, float hi) {
    return __builtin_amdgcn_perm(__float_as_uint(hi), __float_as_uint(lo), 0x07060302u);
}
__device__ __forceinline__ float xlo(unsigned u) {
    union { unsigned u; float f; } c; c.u = u << 16; return c.f;
}
__device__ __forceinline__ float xhi(unsigned u) {
    union { unsigned u; float f; } c; c.u = u & 0xffff0000u; return c.f;
}
__device__ __forceinline__ void barrier_lgkm() {
    asm volatile("s_waitcnt lgkmcnt(0)" ::: "memory");
    __builtin_amdgcn_s_barrier();
}
__device__ __forceinline__ void wait_lgkm() {
    asm volatile("s_waitcnt lgkmcnt(0)" ::: "memory");
}

// pPair[a][h] = (bf16(P2[a][h]) << 16) | bf16(P1[a][h])
// P1 = b_lin + emb@W[:,0:128]^T ; P2 = emb@W[:,128:256]^T
__global__ void precompute_kernel(const float* __restrict__ emb,
                                  const float* __restrict__ w_lin,
                                  const float* __restrict__ b_lin,
                                  unsigned* __restrict__ pPair) {
    __shared__ __align__(16) float erow[HIDDEN];
    const int a = blockIdx.x;
    const int h = threadIdx.x;
    erow[h] = emb[a * HIDDEN + h];
    __syncthreads();
    float a1 = b_lin[h];
    float a2 = 0.f;
    const float* __restrict__ w1 = w_lin + h * 384;
    const float* __restrict__ w2 = w1 + HIDDEN;
#pragma unroll 8
    for (int k = 0; k < HIDDEN; ++k) {
        a1 += erow[k] * w1[k];
        a2 += erow[k] * w2[k];
    }
    const unsigned lo = (unsigned)(unsigned short)f2bf(a1);
    const unsigned hi = ((unsigned)(unsigned short)f2bf(a2)) << 16;
    pPair[a * HIDDEN + h] = hi | lo;
}

struct RawMD {
    float2 ra, rb, rc;   // rbf[e][0..5]
    int ii, jj;          // iv[e], jv[e]
};

__device__ __forceinline__ RawMD load_raw(int st, int l15, int n_edges,
                                          const int* __restrict__ iv,
                                          const int* __restrict__ jv,
                                          const float* __restrict__ rbf) {
    int e = st * 16 + l15;
    int ecl = (e < n_edges) ? e : (n_edges - 1);
    RawMD m;
    const float2* rp = reinterpret_cast<const float2*>(rbf + (size_t)ecl * NRAD);
    m.ra = rp[0];
    m.rb = rp[1];
    m.rc = rp[2];
    m.ii = iv[ecl];
    m.jj = jv[ecl];
    return m;
}

// 32 edges per block-iteration (two 16-edge sub-tiles u=0,1 through ONE
// barrier pair).  Wave w owns channels [32w, 32w+32) = one 128B line/edge:
//  - MFMA output (transposed) lands exactly in that window,
//  - epilogue writes a per-wave bf16 stage (in-wave, lgkm-ordered, NO barrier),
//  - wave stores its own window one tile behind, 8 lanes x 16B = full
//    128B-line bursts, fully decoupled from the block barriers.
// fragS (rbf0 exchange) is the only cross-wave buffer: 2 barriers / 32 edges.
__global__ __launch_bounds__(256, 2)
void edge_mfma_kernel(const int* __restrict__ xv,
                      const float* __restrict__ rbf,
                      const int* __restrict__ iv,
                      const int* __restrict__ jv,
                      const float* __restrict__ w_rbf0,
                      const float* __restrict__ b_rbf0,
                      const float* __restrict__ w_rbf1,
                      const float* __restrict__ w_lin,
                      const unsigned* __restrict__ pPairG,
                      float* __restrict__ out_e1,
                      float* __restrict__ out_e2,
                      int n_edges, int tiles_per_block, int nt32, int n_rows) {
    __shared__ unsigned pps[NEMB * HIDDEN];                    // 48640 B
    __shared__ __align__(16) short fragS[2][16 * 132];         // 8448 B (264B chunk-rows)
    __shared__ __align__(8) unsigned short stg[4][2][32 * 36]; // 18432 B (72B rows, per wave)
    __shared__ __align__(16) short w1a[HIDDEN * 8];            // 2048 B

    const int tid = threadIdx.x;

    // ---- stage packed P table ----
    {
        const int n = (n_rows < NEMB ? n_rows : NEMB) * HIDDEN;
        for (int s = tid; s < n; s += 256) pps[s] = pPairG[s];
    }
    if (tid < HIDDEN) {
        bf16x8 f1;
#pragma unroll
        for (int r = 0; r < NRAD; ++r) f1[r] = f2bf(w_rbf1[tid * NRAD + r]);
        f1[6] = 0; f1[7] = 0;
        *reinterpret_cast<bf16x8*>(&w1a[tid * 8]) = f1;
    }

    const int wid = tid >> 6;
    const int lane = tid & 63;
    const int l15 = lane & 15;
    const int lg = lane >> 4;

    // ---- register-resident w0/b0 for this lane's FIXED k-set ----
    const int kbase = wid * 32 + lg * 8;
    float w0r[8][6], b0r[8];
#pragma unroll
    for (int j = 0; j < 8; ++j) {
        const float2* wp = reinterpret_cast<const float2*>(w_rbf0 + (kbase + j) * NRAD);
        const float2 a = wp[0], b = wp[1], c = wp[2];
        w0r[j][0] = a.x; w0r[j][1] = a.y;
        w0r[j][2] = b.x; w0r[j][3] = b.y;
        w0r[j][4] = c.x; w0r[j][5] = c.y;
        b0r[j] = b_rbf0[kbase + j];
    }

    // ---- W3 fragments in registers (wave w -> nt = 2w, 2w+1) ----
    bf16x8 w3f[2][4];
#pragma unroll
    for (int n2 = 0; n2 < 2; ++n2) {
        const int h = (wid * 2 + n2) * 16 + l15;
        const float* wp = w_lin + h * 384 + 256;
#pragma unroll
        for (int ks = 0; ks < 4; ++ks) {
            const float4* s4 = reinterpret_cast<const float4*>(wp + (ks * 4 + lg) * 8);
            const float4 va = s4[0];
            const float4 vb = s4[1];
            bf16x8 fr;
            fr[0] = f2bf(va.x); fr[1] = f2bf(va.y);
            fr[2] = f2bf(va.z); fr[3] = f2bf(va.w);
            fr[4] = f2bf(vb.x); fr[5] = f2bf(vb.y);
            fr[6] = f2bf(vb.z); fr[7] = f2bf(vb.w);
            w3f[n2][ks] = fr;
        }
    }
    __syncthreads();   // pps + w1a staged

    const int bt = blockIdx.x * tiles_per_block;
    const int btEnd = min(bt + tiles_per_block, nt32);
    if (bt >= btEnd) return;   // uniform per block

    const f32x4 zero4 = (f32x4){0.f, 0.f, 0.f, 0.f};

    // ---- pipeline prologue: MD 2-deep (raw), xv gathers 1-deep ----
    RawMD c0 = load_raw(2 * bt,     l15, n_edges, iv, jv, rbf);
    RawMD c1 = load_raw(2 * bt + 1, l15, n_edges, iv, jv, rbf);
    RawMD x0 = load_raw(2 * bt + 2, l15, n_edges, iv, jv, rbf);
    RawMD x1 = load_raw(2 * bt + 3, l15, n_edges, iv, jv, rbf);
    int c0i = xv[c0.ii], c0j = xv[c0.jj];
    int c1i = xv[c1.ii], c1j = xv[c1.jj];

    for (int t = bt; t < btEnd; ++t) {
        RawMD p0 = load_raw(2 * (t + 2),     l15, n_edges, iv, jv, rbf);
        RawMD p1 = load_raw(2 * (t + 2) + 1, l15, n_edges, iv, jv, rbf);
        const int g0i = xv[x0.ii], g0j = xv[x0.jj];   // x0/x1 loaded last iter
        const int g1i = xv[x1.ii], g1j = xv[x1.jj];

        // ---- A-build (register-only) + frag writes, both sub-tiles ----
        {
            float sv[8];
#pragma unroll
            for (int j = 0; j < 8; ++j) {
                float tv = b0r[j]
                         + c0.ra.x * w0r[j][0] + c0.ra.y * w0r[j][1]
                         + c0.rb.x * w0r[j][2] + c0.rb.y * w0r[j][3]
                         + c0.rc.x * w0r[j][4] + c0.rc.y * w0r[j][5];
                sv[j] = swishf(tv);
            }
            uint4 mf;
            mf.x = pk(sv[0], sv[1]); mf.y = pk(sv[2], sv[3]);
            mf.z = pk(sv[4], sv[5]); mf.w = pk(sv[6], sv[7]);
            *reinterpret_cast<uint4*>(&fragS[0][(wid * 4 + lg) * 132 + l15 * 8]) = mf;
        }
        {
            float sv[8];
#pragma unroll
            for (int j = 0; j < 8; ++j) {
                float tv = b0r[j]
                         + c1.ra.x * w0r[j][0] + c1.ra.y * w0r[j][1]
                         + c1.rb.x * w0r[j][2] + c1.rb.y * w0r[j][3]
                         + c1.rc.x * w0r[j][4] + c1.rc.y * w0r[j][5];
                sv[j] = swishf(tv);
            }
            uint4 mf;
            mf.x = pk(sv[0], sv[1]); mf.y = pk(sv[2], sv[3]);
            mf.z = pk(sv[4], sv[5]); mf.w = pk(sv[6], sv[7]);
            *reinterpret_cast<uint4*>(&fragS[1][(wid * 4 + lg) * 132 + l15 * 8]) = mf;
        }

        // ---- qd = rbf @ w1^T via MFMA (reg/LDS-read only; fills write shadow) ----
        union { uint4 u; bf16x8 b; } rp0, rp1;
        rp0.u = (uint4){0u, 0u, 0u, 0u};
        rp1.u = (uint4){0u, 0u, 0u, 0u};
        if (lg == 0) {
            rp0.u.x = pk(c0.ra.x, c0.ra.y);
            rp0.u.y = pk(c0.rb.x, c0.rb.y);
            rp0.u.z = pk(c0.rc.x, c0.rc.y);
            rp1.u.x = pk(c1.ra.x, c1.ra.y);
            rp1.u.y = pk(c1.rb.x, c1.rb.y);
            rp1.u.z = pk(c1.rc.x, c1.rc.y);
        }
        f32x4 acc2[2][2];
#pragma unroll
        for (int n2 = 0; n2 < 2; ++n2) {
            const bf16x8 aw = *reinterpret_cast<const bf16x8*>(
                &w1a[((wid * 2 + n2) * 16 + l15) * 8]);
            acc2[0][n2] = __builtin_amdgcn_mfma_f32_16x16x32_bf16(aw, rp0.b, zero4, 0, 0, 0);
            acc2[1][n2] = __builtin_amdgcn_mfma_f32_16x16x32_bf16(aw, rp1.b, zero4, 0, 0, 0);
        }

        barrier_lgkm();   // bar1: fragment exchange visible

        f32x4 acc[2][2];
#pragma unroll
        for (int u = 0; u < 2; ++u) {
            bf16x8 bf[4];
#pragma unroll
            for (int ks = 0; ks < 4; ++ks)
                bf[ks] = *reinterpret_cast<const bf16x8*>(
                    &fragS[u][(ks * 4 + lg) * 132 + l15 * 8]);
#pragma unroll
            for (int n2 = 0; n2 < 2; ++n2) acc[u][n2] = zero4;
#pragma unroll
            for (int ks = 0; ks < 4; ++ks)
#pragma unroll
                for (int n2 = 0; n2 < 2; ++n2)
                    acc[u][n2] = __builtin_amdgcn_mfma_f32_16x16x32_bf16(
                        w3f[n2][ks], bf[ks], acc[u][n2], 0, 0, 0);
        }

        barrier_lgkm();   // bar2: fragS reads done in all waves -> reusable

        // ---- store phase for tile t-1 (in-wave, full 128B lines) ----
        if (t != bt) {
            const int tp = t - 1;
#pragma unroll
            for (int arr = 0; arr < 2; ++arr) {
                float* __restrict__ ob = arr ? out_e2 : out_e1;
#pragma unroll
                for (int s = 0; s < 4; ++s) {
                    const int e = 8 * s + (lane >> 3);
                    const uint2 u2v = *reinterpret_cast<const uint2*>(
                        &stg[wid][arr][e * 36 + (lane & 7) * 4]);
                    const int eg = tp * 32 + e;
                    if (eg < n_edges) {
                        f32x4 v;
                        v[0] = xlo(u2v.x); v[1] = xhi(u2v.x);
                        v[2] = xlo(u2v.y); v[3] = xhi(u2v.y);
                        *reinterpret_cast<f32x4*>(
                            ob + (size_t)eg * HIDDEN + wid * 32 + (lane & 7) * 4) = v;
                    }
                }
            }
        }
        wait_lgkm();   // in-wave WAR: stage reads complete before overwrite

        // ---- epilogue: P adds, swish, e2, per-wave bf16 stage writes ----
#pragma unroll
        for (int u = 0; u < 2; ++u) {
            const int xi = u ? c1i : c0i;
            const int xj = u ? c1j : c0j;
            const int row = u * 16 + l15;
#pragma unroll
            for (int n2 = 0; n2 < 2; ++n2) {
                const int ch0 = wid * 32 + n2 * 16 + lg * 4;
                const uint4 r1 = *reinterpret_cast<const uint4*>(&pps[xi * HIDDEN + ch0]);
                const uint4 r2 = *reinterpret_cast<const uint4*>(&pps[xj * HIDDEN + ch0]);
                float pv[4];
                pv[0] = bf2f((unsigned short)(r1.x & 0xffff)) + bf2f((unsigned short)(r2.x >> 16));
                pv[1] = bf2f((unsigned short)(r1.y & 0xffff)) + bf2f((unsigned short)(r2.y >> 16));
                pv[2] = bf2f((unsigned short)(r1.z & 0xffff)) + bf2f((unsigned short)(r2.z >> 16));
                pv[3] = bf2f((unsigned short)(r1.w & 0xffff)) + bf2f((unsigned short)(r2.w >> 16));
                float e1v[4], e2v[4];
#pragma unroll
                for (int q = 0; q < 4; ++q) {
                    const float s = acc[u][n2][q] + pv[q];
                    e1v[q] = swishf(s);
                    e2v[q] = acc2[u][n2][q] * e1v[q];
                }
                const int so = row * 36 + n2 * 16 + lg * 4;
                *reinterpret_cast<uint2*>(&stg[wid][0][so]) =
                    make_uint2(pk(e1v[0], e1v[1]), pk(e1v[2], e1v[3]));
                *reinterpret_cast<uint2*>(&stg[wid][1][so]) =
                    make_uint2(pk(e2v[0], e2v[1]), pk(e2v[2], e2v[3]));
            }
        }

        c0 = x0; c1 = x1; x0 = p0; x1 = p1;
        c0i = g0i; c0j = g0j; c1i = g1i; c1j = g1j;
    }

    // ---- drain: store phase for the last tile ----
    wait_lgkm();
    {
        const int tp = btEnd - 1;
#pragma unroll
        for (int arr = 0; arr < 2; ++arr) {
            float* __restrict__ ob = arr ? out_e2 : out_e1;
#pragma unroll
            for (int s = 0; s < 4; ++s) {
                const int e = 8 * s + (lane >> 3);
                const uint2 u2v = *reinterpret_cast<const uint2*>(
                    &stg[wid][arr][e * 36 + (lane & 7) * 4]);
                const int eg = tp * 32 + e;
                if (eg < n_edges) {
                    f32x4 v;
                    v[0] = xlo(u2v.x); v[1] = xhi(u2v.x);
                    v[2] = xlo(u2v.y); v[3] = xhi(u2v.y);
                    *reinterpret_cast<f32x4*>(
                        ob + (size_t)eg * HIDDEN + wid * 32 + (lane & 7) * 4) = v;
                }
            }
        }
    }
}

extern "C" void kernel_launch(void* const* d_in, const int* in_sizes, int n_in,
                              void* d_out, int out_size, void* d_ws, size_t ws_size,
                              hipStream_t stream) {
    const int*   xv     = (const int*)  d_in[0];
    const float* rbf    = (const float*)d_in[1];
    const int*   iv     = (const int*)  d_in[2];
    const int*   jv     = (const int*)  d_in[3];
    const float* emb    = (const float*)d_in[4];
    const float* w_rbf0 = (const float*)d_in[5];
    const float* b_rbf0 = (const float*)d_in[6];
    const float* w_lin  = (const float*)d_in[7];
    const float* b_lin  = (const float*)d_in[8];
    const float* w_rbf1 = (const float*)d_in[9];

    const int n_edges = in_sizes[2];
    const int n_emb_rows = in_sizes[4] / HIDDEN;   // 95

    unsigned* pPair = (unsigned*)d_ws;             // 95*128*4 = 48640 B

    float* out_e1 = (float*)d_out;
    float* out_e2 = out_e1 + (size_t)n_edges * HIDDEN;

    precompute_kernel<<<n_emb_rows, HIDDEN, 0, stream>>>(emb, w_lin, b_lin, pPair);

    const int nt32 = (n_edges + 31) / 32;
    const int grid = 512;                          // 2 blocks/CU (LDS-limited)
    const int tpb = (nt32 + grid - 1) / grid;
    edge_mfma_kernel<<<grid, 256, 0, stream>>>(xv, rbf, iv, jv,
                                               w_rbf0, b_rbf0, w_rbf1, w_lin,
                                               pPair, out_e1, out_e2,
                                               n_edges, tpb, nt32, n_emb_rows);
}